// Round 9
// baseline (503.623 us; speedup 1.0000x reference)
//
#include <hip/hip_runtime.h>

#define B_N 65536
#define M_N 1000000
#define E_N 1310720
#define IN_D 64
#define OUT_D 32
#define BM 128   // rows per block in hproj part
#define XS2 72   // sx row stride in SHORTS (144 B, 16B-aligned rows)
#define NCT 5    // col-tiles: 4 x 16 h-cols + 1 tile holding folded a-dot cols
#define NFRAG (NCT * 2)
#define HP_B ((M_N + BM - 1) / BM)      // 7813 hproj blocks
#define SC_B ((2 * E_N + 255) / 256)    // 10240 scatter blocks

typedef __attribute__((ext_vector_type(8))) short bf16x8;
typedef __attribute__((ext_vector_type(4))) float f32x4;

__device__ __forceinline__ unsigned short f2bf(float f) {
  unsigned u = __float_as_uint(f);
  u += 0x7fffu + ((u >> 16) & 1u);
  return (unsigned short)(u >> 16);
}
__device__ __forceinline__ unsigned pk2(float a, float b) {
  return (unsigned)f2bf(a) | ((unsigned)f2bf(b) << 16);
}
__device__ __forceinline__ float bf2f(unsigned short s) {
  return __uint_as_float(((unsigned)s) << 16);
}

// Grid-stride zero fill (runtime fillBuffer path for small fills is ~1.8 GB/s).
__global__ __launch_bounds__(256) void k_zero(uint4* __restrict__ p, int n16) {
  int i = blockIdx.x * 256 + threadIdx.x;
  int stride = gridDim.x * 256;
  for (; i < n16; i += stride) p[i] = (uint4){0u, 0u, 0u, 0u};
}

// Fused: block 0 packs B_ext MFMA fragments; blocks 1.. histogram the edges.
__global__ __launch_bounds__(256) void k_pre(
    const float* __restrict__ Wb, const float* __restrict__ ab,
    const float* __restrict__ Wu, const float* __restrict__ au,
    unsigned* __restrict__ frag_buf,
    const int* __restrict__ prow, const int* __restrict__ nrow,
    int* __restrict__ hist)
{
  int t = threadIdx.x;
  if (blockIdx.x == 0) {
    // B_ext = [Wb | Wu | Wb@ab_lo | Wb@ab_hi | Wu@au_lo | Wu@au_hi | 0..]
    // frag q = ct*2+S; lane l elem i: k = 32*S+8*(l>>4)+i, n = 16*ct+(l&15).
    for (int p = t; p < NFRAG * 64 * 4; p += 256) {
      int q = p >> 8;
      int rem = p & 255;
      int l = rem >> 2;
      int d = rem & 3;
      int ct = q >> 1, S = q & 1;
      int kb = 32 * S + 8 * (l >> 4);
      int n = 16 * ct + (l & 15);
      float v[2];
      #pragma unroll
      for (int e = 0; e < 2; ++e) {
        int kk = kb + 2 * d + e;
        float val;
        if (n < 32) val = Wb[kk * 32 + n];
        else if (n < 64) val = Wu[kk * 32 + (n - 32)];
        else if (n < 68) {
          const float* W = (n < 66) ? Wb : Wu;
          const float* av = (n < 66) ? ab : au;
          int hi = (n & 1) ? 32 : 0;
          float acc = 0.f;
          for (int j = 0; j < 32; ++j) acc = fmaf(W[kk * 32 + j], av[hi + j], acc);
          val = acc;
        } else val = 0.f;
        v[e] = val;
      }
      frag_buf[p] = pk2(v[0], v[1]);
    }
  } else {
    int i = (blockIdx.x - 1) * 256 + t;
    if (i < E_N) atomicAdd(&hist[prow[i]], 1);
    else if (i < 2 * E_N) atomicAdd(&hist[B_N + nrow[i - E_N]], 1);
  }
}

// Three-phase parallel exclusive scan of hist[2*B_N].
__global__ __launch_bounds__(256) void k_scan1(
    const int* __restrict__ hist, int* __restrict__ bsum)
{
  __shared__ int s[256];
  int t = threadIdx.x;
  int v = hist[blockIdx.x * 256 + t];
  s[t] = v;
  __syncthreads();
  for (int off = 1; off < 256; off <<= 1) {
    int add = (t >= off) ? s[t - off] : 0;
    __syncthreads();
    s[t] += add;
    __syncthreads();
  }
  if (t == 255) bsum[blockIdx.x] = s[255];
}

__global__ __launch_bounds__(512) void k_scan2(
    int* __restrict__ bsum, int* __restrict__ boff, int* __restrict__ start)
{
  __shared__ int s[512];
  int t = threadIdx.x;
  int v = bsum[t];
  s[t] = v;
  __syncthreads();
  for (int off = 1; off < 512; off <<= 1) {
    int add = (t >= off) ? s[t - off] : 0;
    __syncthreads();
    s[t] += add;
    __syncthreads();
  }
  boff[t] = s[t] - v;  // exclusive
  if (t == 0) start[2 * B_N] = 2 * E_N;
}

__global__ __launch_bounds__(256) void k_scan3(
    const int* __restrict__ hist, const int* __restrict__ boff,
    int* __restrict__ start, int* __restrict__ cursor)
{
  __shared__ int s[256];
  int t = threadIdx.x;
  int i = blockIdx.x * 256 + t;
  int v = hist[i];
  s[t] = v;
  __syncthreads();
  for (int off = 1; off < 256; off <<= 1) {
    int add = (t >= off) ? s[t - off] : 0;
    __syncthreads();
    s[t] += add;
    __syncthreads();
  }
  int ex = boff[blockIdx.x] + s[t] - v;
  start[i] = ex;
  cursor[i] = ex;
}

// Fused mid: blocks [0, HP_B) = MFMA h-projection; blocks [HP_B, +SC_B) =
// edge scatter. Independent tasks share the machine in one launch.
__global__ __launch_bounds__(256) void k_mid(
    const float* __restrict__ emb, const int* __restrict__ uids,
    const unsigned* __restrict__ frag_buf,
    unsigned short* __restrict__ hb, unsigned short* __restrict__ hu,
    float* __restrict__ adb, float* __restrict__ adu,
    float* __restrict__ asb, float* __restrict__ asu,
    const int* __restrict__ prow, const int* __restrict__ pcol,
    const int* __restrict__ nrow, const int* __restrict__ ncol,
    int* __restrict__ cursor, int* __restrict__ cols_s)
{
  __shared__ int suid[BM];
  __shared__ unsigned short sx[BM * XS2];  // 18.4 KB; reused by epilogue
  int t = threadIdx.x;

  if (blockIdx.x >= HP_B) {
    // ---- scatter part ----
    int i = (blockIdx.x - HP_B) * 256 + t;
    int r, c;
    if (i < E_N) { r = prow[i]; c = pcol[i]; }
    else if (i < 2 * E_N) { r = B_N + nrow[i - E_N]; c = ncol[i - E_N]; }
    else return;
    int pos = atomicAdd(&cursor[r], 1);
    cols_s[pos] = c;
    return;
  }

  // ---- hproj part ----
  int nbase = blockIdx.x * BM;
  if (t < BM) suid[t] = (nbase + t < M_N) ? uids[nbase + t] : 0;
  __syncthreads();

  int chunk = t & 15, rb = t >> 4;
  #pragma unroll
  for (int i = 0; i < BM / 16; ++i) {
    int row = i * 16 + rb;
    float4 v = ((const float4*)emb)[(size_t)suid[row] * 16 + chunk];
    uint2 p;
    p.x = pk2(v.x, v.y);
    p.y = pk2(v.z, v.w);
    *(uint2*)&sx[row * XS2 + chunk * 4] = p;
  }
  __syncthreads();

  int l = t & 63, w = t >> 6;
  bf16x8 bf[NFRAG];
  #pragma unroll
  for (int q = 0; q < NFRAG; ++q)
    bf[q] = *(const bf16x8*)&frag_buf[(q * 64 + l) * 4];

  f32x4 acc[2][NCT];
  #pragma unroll
  for (int rt = 0; rt < 2; ++rt)
    #pragma unroll
    for (int ct = 0; ct < NCT; ++ct)
      acc[rt][ct] = (f32x4){0.f, 0.f, 0.f, 0.f};

  int wr0 = w * 32;
  #pragma unroll
  for (int rt = 0; rt < 2; ++rt) {
    const unsigned short* arow =
        &sx[(wr0 + rt * 16 + (l & 15)) * XS2 + (l >> 4) * 8];
    bf16x8 a0 = *(const bf16x8*)(arow);        // k 0..31 slice
    bf16x8 a1 = *(const bf16x8*)(arow + 32);   // k 32..63 slice
    #pragma unroll
    for (int ct = 0; ct < NCT; ++ct) {
      acc[rt][ct] = __builtin_amdgcn_mfma_f32_16x16x32_bf16(
          a0, bf[2 * ct + 0], acc[rt][ct], 0, 0, 0);
      acc[rt][ct] = __builtin_amdgcn_mfma_f32_16x16x32_bf16(
          a1, bf[2 * ct + 1], acc[rt][ct], 0, 0, 0);
    }
  }

  __syncthreads();  // staging reads done; reuse sx as repack buffer
  unsigned short* sb = sx;             // [BM][32] bf16 h_bal
  unsigned short* su = sx + BM * 32;   // [BM][32] bf16 h_unbal

  // D: col = lane&15, row = (lane>>4)*4 + reg (m89-verified).
  int g = l >> 4, cc = l & 15;
  #pragma unroll
  for (int rt = 0; rt < 2; ++rt) {
    int rl0 = wr0 + rt * 16 + g * 4;
    #pragma unroll
    for (int r = 0; r < 4; ++r) {
      int rl = rl0 + r;
      #pragma unroll
      for (int ct = 0; ct < 4; ++ct) {
        unsigned short hv = f2bf(acc[rt][ct][r]);
        if (ct < 2) sb[rl * 32 + ct * 16 + cc] = hv;
        else su[rl * 32 + (ct - 2) * 16 + cc] = hv;
      }
      int row = nbase + rl;
      if (row < M_N) {
        float dv = acc[rt][4][r];
        if (cc == 1) adb[row] = dv;
        else if (cc == 3) adu[row] = dv;
        else if (cc == 0) { if (row < B_N) asb[row] = dv; }
        else if (cc == 2) { if (row < B_N) asu[row] = dv; }
      }
    }
  }
  __syncthreads();

  // Stream out: BM rows x 64B per buffer = 512 uint4 each; 2 per thread.
  const uint4* sb4 = (const uint4*)sb;
  const uint4* su4 = (const uint4*)su;
  uint4* hb4 = (uint4*)(hb + (size_t)nbase * 32);
  uint4* hu4 = (uint4*)(hu + (size_t)nbase * 32);
  int maxq = (M_N - nbase) * 4;  // uint4s allowed (4 per row)
  #pragma unroll
  for (int k = 0; k < 2; ++k) {
    int idx = t + k * 256;
    if (idx < maxq) {
      hb4[idx] = sb4[idx];
      hu4[idx] = su4[idx];
    }
  }
}

// Aggregation: one 32-lane group per (branch,row); no atomics; fused elu+out.
__global__ __launch_bounds__(256) void k_agg(
    const int* __restrict__ start, const int* __restrict__ cols_s,
    const int* __restrict__ selfc,
    const unsigned short* __restrict__ hb, const unsigned short* __restrict__ hu,
    const float* __restrict__ adb, const float* __restrict__ asb,
    const float* __restrict__ adu, const float* __restrict__ asu,
    float* __restrict__ out)
{
  int g = blockIdx.x * 8 + (threadIdx.x >> 5);
  int lane = threadIdx.x & 31;
  if (g >= 2 * B_N) return;
  int br = g >> 16;
  int r = g & (B_N - 1);
  const unsigned short* h = br ? hu : hb;
  const float* adst = br ? adu : adb;
  float asr = (br ? asu : asb)[r];

  int c0 = selfc[r];
  float acc, den;
  {
    float s = asr + adst[c0];
    float sc = s > 0.f ? s : 0.2f * s;
    float ev = __expf(-sc);
    acc = ev * bf2f(h[((size_t)c0 << 5) + lane]);
    den = ev;
  }

  int s0 = start[g], s1 = start[g + 1];
  for (int base = s0; base < s1; base += 32) {
    int rem = s1 - base;
    int c = (lane < rem) ? cols_s[base + lane] : c0;
    float ad = adst[c];
    float s = asr + ad;
    float sc = s > 0.f ? s : 0.2f * s;
    float ev = (lane < rem) ? __expf(-sc) : 0.f;
    float evs = ev;
    #pragma unroll
    for (int off = 16; off > 0; off >>= 1) evs += __shfl_xor(evs, off, 32);
    den += evs;

    int m = rem < 32 ? rem : 32;
    int mr = (m + 7) & ~7;  // j+q stays < 32: no shfl wraparound
    for (int j = 0; j < mr; j += 8) {
      int cj[8];
      float ej[8];
      #pragma unroll
      for (int q = 0; q < 8; ++q) {
        cj[q] = __shfl(c, j + q, 32);
        ej[q] = __shfl(ev, j + q, 32);
      }
      float hv[8];
      #pragma unroll
      for (int q = 0; q < 8; ++q)
        hv[q] = bf2f(h[((size_t)cj[q] << 5) + lane]);
      #pragma unroll
      for (int q = 0; q < 8; ++q) acc = fmaf(ej[q], hv[q], acc);
    }
  }

  float x = acc / den;
  out[((size_t)g << 5) + lane] = (x > 0.f) ? x : (__expf(x) - 1.f);
}

extern "C" void kernel_launch(void* const* d_in, const int* in_sizes, int n_in,
                              void* d_out, int out_size, void* d_ws, size_t ws_size,
                              hipStream_t stream) {
  const float* emb = (const float*)d_in[0];
  const float* Wb  = (const float*)d_in[1];
  const float* ab  = (const float*)d_in[2];
  const float* Wu  = (const float*)d_in[3];
  const float* au  = (const float*)d_in[4];
  const int* uids  = (const int*)d_in[5];
  const int* selfc = (const int*)d_in[6];
  const int* prow  = (const int*)d_in[7];
  const int* pcol  = (const int*)d_in[8];
  const int* nrow  = (const int*)d_in[9];
  const int* ncol  = (const int*)d_in[10];
  float* out = (float*)d_out;

  char* ws = (char*)d_ws;
  size_t off = 0;
  auto alloc = [&](size_t bytes) -> void* {
    void* p = ws + off;
    off += (bytes + 255) & ~(size_t)255;
    return p;
  };
  unsigned short* hb = (unsigned short*)alloc((size_t)M_N * OUT_D * 2);
  unsigned short* hu = (unsigned short*)alloc((size_t)M_N * OUT_D * 2);
  float* adb = (float*)alloc((size_t)M_N * 4);
  float* adu = (float*)alloc((size_t)M_N * 4);
  float* asb = (float*)alloc((size_t)B_N * 4);
  float* asu = (float*)alloc((size_t)B_N * 4);
  int* hist   = (int*)alloc((size_t)2 * B_N * 4);
  int* start  = (int*)alloc(((size_t)2 * B_N + 1) * 4);
  int* cursor = (int*)alloc((size_t)2 * B_N * 4);
  int* cols_s = (int*)alloc((size_t)2 * E_N * 4);
  unsigned* frag_buf = (unsigned*)alloc((size_t)NFRAG * 64 * 4 * 4);
  int* bsum = (int*)alloc(512 * 4);
  int* boff = (int*)alloc(512 * 4);

  k_zero<<<128, 256, 0, stream>>>((uint4*)hist, (2 * B_N * 4) / 16);

  k_pre<<<1 + SC_B, 256, 0, stream>>>(Wb, ab, Wu, au, frag_buf,
                                      prow, nrow, hist);
  k_scan1<<<512, 256, 0, stream>>>(hist, bsum);
  k_scan2<<<1, 512, 0, stream>>>(bsum, boff, start);
  k_scan3<<<512, 256, 0, stream>>>(hist, boff, start, cursor);

  k_mid<<<HP_B + SC_B, 256, 0, stream>>>(emb, uids, frag_buf,
                                         hb, hu, adb, adu, asb, asu,
                                         prow, pcol, nrow, ncol,
                                         cursor, cols_s);

  k_agg<<<(2 * B_N + 7) / 8, 256, 0, stream>>>(start, cols_s, selfc,
                                               hb, hu, adb, asb, adu, asu, out);
}

// Round 10
// 354.509 us; speedup vs baseline: 1.4206x; 1.4206x over previous
//
#include <hip/hip_runtime.h>

#define B_N 65536
#define M_N 1000000
#define E_N 1310720
#define IN_D 64
#define OUT_D 32
#define BM 128   // rows per block in hproj part
#define XS2 72   // sx row stride in SHORTS (144 B, 16B-aligned rows)
#define NCT 5    // col-tiles: 4 x 16 h-cols + 1 tile holding folded a-dot cols
#define NFRAG (NCT * 2)
#define HP_B ((M_N + BM - 1) / BM)      // 7813 hproj blocks
#define SC_B ((2 * E_N + 255) / 256)    // 10240 scatter blocks

typedef __attribute__((ext_vector_type(8))) short bf16x8;
typedef __attribute__((ext_vector_type(4))) float f32x4;

__device__ __forceinline__ unsigned short f2bf(float f) {
  unsigned u = __float_as_uint(f);
  u += 0x7fffu + ((u >> 16) & 1u);
  return (unsigned short)(u >> 16);
}
__device__ __forceinline__ unsigned pk2(float a, float b) {
  return (unsigned)f2bf(a) | ((unsigned)f2bf(b) << 16);
}
__device__ __forceinline__ float bf2f(unsigned short s) {
  return __uint_as_float(((unsigned)s) << 16);
}

// Grid-stride zero fill (runtime fillBuffer path for small fills is ~1.8 GB/s).
__global__ __launch_bounds__(256) void k_zero(uint4* __restrict__ p, int n16) {
  int i = blockIdx.x * 256 + threadIdx.x;
  int stride = gridDim.x * 256;
  for (; i < n16; i += stride) p[i] = (uint4){0u, 0u, 0u, 0u};
}

// Fused: block 0 packs B_ext MFMA fragments; blocks 1.. histogram the edges.
__global__ __launch_bounds__(256) void k_pre(
    const float* __restrict__ Wb, const float* __restrict__ ab,
    const float* __restrict__ Wu, const float* __restrict__ au,
    unsigned* __restrict__ frag_buf,
    const int* __restrict__ prow, const int* __restrict__ nrow,
    int* __restrict__ hist)
{
  int t = threadIdx.x;
  if (blockIdx.x == 0) {
    // B_ext = [Wb | Wu | Wb@ab_lo | Wb@ab_hi | Wu@au_lo | Wu@au_hi | 0..]
    // frag q = ct*2+S; lane l elem i: k = 32*S+8*(l>>4)+i, n = 16*ct+(l&15).
    for (int p = t; p < NFRAG * 64 * 4; p += 256) {
      int q = p >> 8;
      int rem = p & 255;
      int l = rem >> 2;
      int d = rem & 3;
      int ct = q >> 1, S = q & 1;
      int kb = 32 * S + 8 * (l >> 4);
      int n = 16 * ct + (l & 15);
      float v[2];
      #pragma unroll
      for (int e = 0; e < 2; ++e) {
        int kk = kb + 2 * d + e;
        float val;
        if (n < 32) val = Wb[kk * 32 + n];
        else if (n < 64) val = Wu[kk * 32 + (n - 32)];
        else if (n < 68) {
          const float* W = (n < 66) ? Wb : Wu;
          const float* av = (n < 66) ? ab : au;
          int hi = (n & 1) ? 32 : 0;
          float acc = 0.f;
          for (int j = 0; j < 32; ++j) acc = fmaf(W[kk * 32 + j], av[hi + j], acc);
          val = acc;
        } else val = 0.f;
        v[e] = val;
      }
      frag_buf[p] = pk2(v[0], v[1]);
    }
  } else {
    int i = (blockIdx.x - 1) * 256 + t;
    if (i < E_N) atomicAdd(&hist[prow[i]], 1);
    else if (i < 2 * E_N) atomicAdd(&hist[B_N + nrow[i - E_N]], 1);
  }
}

// Three-phase parallel exclusive scan of hist[2*B_N].
__global__ __launch_bounds__(256) void k_scan1(
    const int* __restrict__ hist, int* __restrict__ bsum)
{
  __shared__ int s[256];
  int t = threadIdx.x;
  int v = hist[blockIdx.x * 256 + t];
  s[t] = v;
  __syncthreads();
  for (int off = 1; off < 256; off <<= 1) {
    int add = (t >= off) ? s[t - off] : 0;
    __syncthreads();
    s[t] += add;
    __syncthreads();
  }
  if (t == 255) bsum[blockIdx.x] = s[255];
}

__global__ __launch_bounds__(512) void k_scan2(
    int* __restrict__ bsum, int* __restrict__ boff, int* __restrict__ start)
{
  __shared__ int s[512];
  int t = threadIdx.x;
  int v = bsum[t];
  s[t] = v;
  __syncthreads();
  for (int off = 1; off < 512; off <<= 1) {
    int add = (t >= off) ? s[t - off] : 0;
    __syncthreads();
    s[t] += add;
    __syncthreads();
  }
  boff[t] = s[t] - v;  // exclusive
  if (t == 0) start[2 * B_N] = 2 * E_N;
}

__global__ __launch_bounds__(256) void k_scan3(
    const int* __restrict__ hist, const int* __restrict__ boff,
    int* __restrict__ start, int* __restrict__ cursor)
{
  __shared__ int s[256];
  int t = threadIdx.x;
  int i = blockIdx.x * 256 + t;
  int v = hist[i];
  s[t] = v;
  __syncthreads();
  for (int off = 1; off < 256; off <<= 1) {
    int add = (t >= off) ? s[t - off] : 0;
    __syncthreads();
    s[t] += add;
    __syncthreads();
  }
  int ex = boff[blockIdx.x] + s[t] - v;
  start[i] = ex;
  cursor[i] = ex;
}

// Fused mid with INTERLEAVED roles: ~4 of every 7 blocks scatter, 3 hproj, so
// both populations are co-resident and their stalls overlap (scatter is
// fabric/atomic-latency-bound; hproj is HBM/MFMA-bound).
__global__ __launch_bounds__(256) void k_mid(
    const float* __restrict__ emb, const int* __restrict__ uids,
    const unsigned* __restrict__ frag_buf,
    unsigned short* __restrict__ hb, unsigned short* __restrict__ hu,
    float* __restrict__ adb, float* __restrict__ adu,
    float* __restrict__ asb, float* __restrict__ asu,
    const int* __restrict__ prow, const int* __restrict__ pcol,
    const int* __restrict__ nrow, const int* __restrict__ ncol,
    int* __restrict__ cursor, int* __restrict__ cols_s)
{
  __shared__ int suid[BM];
  __shared__ unsigned short sx[BM * XS2];  // 18.4 KB; reused by epilogue
  int t = threadIdx.x;

  // Role assignment: pattern (b%7)<4 -> scatter, else hproj; s_id/h_id count
  // pattern-assigned blocks before b; fall back when one side is exhausted.
  int b = blockIdx.x;
  int r7 = b % 7;
  int s_id = (b / 7) * 4 + (r7 < 4 ? r7 : 4);
  int h_id = b - s_id;
  bool do_scatter;
  if (s_id >= SC_B)      { do_scatter = false; h_id = b - SC_B; }
  else if (h_id >= HP_B) { do_scatter = true;  s_id = b - HP_B; }
  else                   { do_scatter = (r7 < 4); }

  if (do_scatter) {
    int i = s_id * 256 + t;
    int r, c;
    if (i < E_N) { r = prow[i]; c = pcol[i]; }
    else if (i < 2 * E_N) { r = B_N + nrow[i - E_N]; c = ncol[i - E_N]; }
    else return;
    int pos = atomicAdd(&cursor[r], 1);
    cols_s[pos] = c;
    return;
  }

  // ---- hproj part ----
  int nbase = h_id * BM;
  if (t < BM) suid[t] = (nbase + t < M_N) ? uids[nbase + t] : 0;
  __syncthreads();

  int chunk = t & 15, rb = t >> 4;
  #pragma unroll
  for (int i = 0; i < BM / 16; ++i) {
    int row = i * 16 + rb;
    float4 v = ((const float4*)emb)[(size_t)suid[row] * 16 + chunk];
    uint2 p;
    p.x = pk2(v.x, v.y);
    p.y = pk2(v.z, v.w);
    *(uint2*)&sx[row * XS2 + chunk * 4] = p;
  }
  __syncthreads();

  int l = t & 63, w = t >> 6;
  bf16x8 bf[NFRAG];
  #pragma unroll
  for (int q = 0; q < NFRAG; ++q)
    bf[q] = *(const bf16x8*)&frag_buf[(q * 64 + l) * 4];

  f32x4 acc[2][NCT];
  #pragma unroll
  for (int rt = 0; rt < 2; ++rt)
    #pragma unroll
    for (int ct = 0; ct < NCT; ++ct)
      acc[rt][ct] = (f32x4){0.f, 0.f, 0.f, 0.f};

  int wr0 = w * 32;
  #pragma unroll
  for (int rt = 0; rt < 2; ++rt) {
    const unsigned short* arow =
        &sx[(wr0 + rt * 16 + (l & 15)) * XS2 + (l >> 4) * 8];
    bf16x8 a0 = *(const bf16x8*)(arow);        // k 0..31 slice
    bf16x8 a1 = *(const bf16x8*)(arow + 32);   // k 32..63 slice
    #pragma unroll
    for (int ct = 0; ct < NCT; ++ct) {
      acc[rt][ct] = __builtin_amdgcn_mfma_f32_16x16x32_bf16(
          a0, bf[2 * ct + 0], acc[rt][ct], 0, 0, 0);
      acc[rt][ct] = __builtin_amdgcn_mfma_f32_16x16x32_bf16(
          a1, bf[2 * ct + 1], acc[rt][ct], 0, 0, 0);
    }
  }

  __syncthreads();  // staging reads done; reuse sx as repack buffer
  unsigned short* sb = sx;             // [BM][32] bf16 h_bal
  unsigned short* su = sx + BM * 32;   // [BM][32] bf16 h_unbal

  // D: col = lane&15, row = (lane>>4)*4 + reg (m89-verified).
  int g = l >> 4, cc = l & 15;
  #pragma unroll
  for (int rt = 0; rt < 2; ++rt) {
    int rl0 = wr0 + rt * 16 + g * 4;
    #pragma unroll
    for (int r = 0; r < 4; ++r) {
      int rl = rl0 + r;
      #pragma unroll
      for (int ct = 0; ct < 4; ++ct) {
        unsigned short hv = f2bf(acc[rt][ct][r]);
        if (ct < 2) sb[rl * 32 + ct * 16 + cc] = hv;
        else su[rl * 32 + (ct - 2) * 16 + cc] = hv;
      }
      int row = nbase + rl;
      if (row < M_N) {
        float dv = acc[rt][4][r];
        if (cc == 1) adb[row] = dv;
        else if (cc == 3) adu[row] = dv;
        else if (cc == 0) { if (row < B_N) asb[row] = dv; }
        else if (cc == 2) { if (row < B_N) asu[row] = dv; }
      }
    }
  }
  __syncthreads();

  // Stream out: BM rows x 64B per buffer = 512 uint4 each; 2 per thread.
  const uint4* sb4 = (const uint4*)sb;
  const uint4* su4 = (const uint4*)su;
  uint4* hb4 = (uint4*)(hb + (size_t)nbase * 32);
  uint4* hu4 = (uint4*)(hu + (size_t)nbase * 32);
  int maxq = (M_N - nbase) * 4;  // uint4s allowed (4 per row)
  #pragma unroll
  for (int k = 0; k < 2; ++k) {
    int idx = t + k * 256;
    if (idx < maxq) {
      hb4[idx] = sb4[idx];
      hu4[idx] = su4[idx];
    }
  }
}

// Aggregation: one 32-lane group per (branch,row); no atomics; fused elu+out.
__global__ __launch_bounds__(256) void k_agg(
    const int* __restrict__ start, const int* __restrict__ cols_s,
    const int* __restrict__ selfc,
    const unsigned short* __restrict__ hb, const unsigned short* __restrict__ hu,
    const float* __restrict__ adb, const float* __restrict__ asb,
    const float* __restrict__ adu, const float* __restrict__ asu,
    float* __restrict__ out)
{
  int g = blockIdx.x * 8 + (threadIdx.x >> 5);
  int lane = threadIdx.x & 31;
  if (g >= 2 * B_N) return;
  int br = g >> 16;
  int r = g & (B_N - 1);
  const unsigned short* h = br ? hu : hb;
  const float* adst = br ? adu : adb;
  float asr = (br ? asu : asb)[r];

  int c0 = selfc[r];
  float acc, den;
  {
    float s = asr + adst[c0];
    float sc = s > 0.f ? s : 0.2f * s;
    float ev = __expf(-sc);
    acc = ev * bf2f(h[((size_t)c0 << 5) + lane]);
    den = ev;
  }

  int s0 = start[g], s1 = start[g + 1];
  for (int base = s0; base < s1; base += 32) {
    int rem = s1 - base;
    int c = (lane < rem) ? cols_s[base + lane] : c0;
    float ad = adst[c];
    float s = asr + ad;
    float sc = s > 0.f ? s : 0.2f * s;
    float ev = (lane < rem) ? __expf(-sc) : 0.f;
    float evs = ev;
    #pragma unroll
    for (int off = 16; off > 0; off >>= 1) evs += __shfl_xor(evs, off, 32);
    den += evs;

    int m = rem < 32 ? rem : 32;
    int mr = (m + 7) & ~7;  // j+q stays < 32: no shfl wraparound
    for (int j = 0; j < mr; j += 8) {
      int cj[8];
      float ej[8];
      #pragma unroll
      for (int q = 0; q < 8; ++q) {
        cj[q] = __shfl(c, j + q, 32);
        ej[q] = __shfl(ev, j + q, 32);
      }
      float hv[8];
      #pragma unroll
      for (int q = 0; q < 8; ++q)
        hv[q] = bf2f(h[((size_t)cj[q] << 5) + lane]);
      #pragma unroll
      for (int q = 0; q < 8; ++q) acc = fmaf(ej[q], hv[q], acc);
    }
  }

  float x = acc / den;
  out[((size_t)g << 5) + lane] = (x > 0.f) ? x : (__expf(x) - 1.f);
}

extern "C" void kernel_launch(void* const* d_in, const int* in_sizes, int n_in,
                              void* d_out, int out_size, void* d_ws, size_t ws_size,
                              hipStream_t stream) {
  const float* emb = (const float*)d_in[0];
  const float* Wb  = (const float*)d_in[1];
  const float* ab  = (const float*)d_in[2];
  const float* Wu  = (const float*)d_in[3];
  const float* au  = (const float*)d_in[4];
  const int* uids  = (const int*)d_in[5];
  const int* selfc = (const int*)d_in[6];
  const int* prow  = (const int*)d_in[7];
  const int* pcol  = (const int*)d_in[8];
  const int* nrow  = (const int*)d_in[9];
  const int* ncol  = (const int*)d_in[10];
  float* out = (float*)d_out;

  char* ws = (char*)d_ws;
  size_t off = 0;
  auto alloc = [&](size_t bytes) -> void* {
    void* p = ws + off;
    off += (bytes + 255) & ~(size_t)255;
    return p;
  };
  unsigned short* hb = (unsigned short*)alloc((size_t)M_N * OUT_D * 2);
  unsigned short* hu = (unsigned short*)alloc((size_t)M_N * OUT_D * 2);
  float* adb = (float*)alloc((size_t)M_N * 4);
  float* adu = (float*)alloc((size_t)M_N * 4);
  float* asb = (float*)alloc((size_t)B_N * 4);
  float* asu = (float*)alloc((size_t)B_N * 4);
  int* hist   = (int*)alloc((size_t)2 * B_N * 4);
  int* start  = (int*)alloc(((size_t)2 * B_N + 1) * 4);
  int* cursor = (int*)alloc((size_t)2 * B_N * 4);
  int* cols_s = (int*)alloc((size_t)2 * E_N * 4);
  unsigned* frag_buf = (unsigned*)alloc((size_t)NFRAG * 64 * 4 * 4);
  int* bsum = (int*)alloc(512 * 4);
  int* boff = (int*)alloc(512 * 4);

  k_zero<<<128, 256, 0, stream>>>((uint4*)hist, (2 * B_N * 4) / 16);

  k_pre<<<1 + SC_B, 256, 0, stream>>>(Wb, ab, Wu, au, frag_buf,
                                      prow, nrow, hist);
  k_scan1<<<512, 256, 0, stream>>>(hist, bsum);
  k_scan2<<<1, 512, 0, stream>>>(bsum, boff, start);
  k_scan3<<<512, 256, 0, stream>>>(hist, boff, start, cursor);

  k_mid<<<HP_B + SC_B, 256, 0, stream>>>(emb, uids, frag_buf,
                                         hb, hu, adb, adu, asb, asu,
                                         prow, pcol, nrow, ncol,
                                         cursor, cols_s);

  k_agg<<<(2 * B_N + 7) / 8, 256, 0, stream>>>(start, cols_s, selfc,
                                               hb, hu, adb, asb, adu, asu, out);
}